// Round 6
// baseline (59.131 us; speedup 1.0000x reference)
//
#include <hip/hip_runtime.h>

#define WN 128
#define KN 32
#define CN 9
#define NBND 129           // W+1 boundary positions
#define NEGF (-1e30f)
#define CW 16              // DP/edge chunk width (windows)
#define ZB 2048            // zero-fill blocks

// jnp floor-mod based wrap: (x + pi) % (2pi) - pi
__device__ __forceinline__ float wrapf(float x) {
    const float PIf  = 3.14159265358979323846f;
    const float TPIf = 6.28318530717958647692f;
    float a = x + PIf;
    float r = fmodf(a, TPIf);
    if (r < 0.0f) r += TPIf;
    return r - PIf;
}

// Fused kernel: blocks 0..B-1 = per-batch {snr stage, chunked edge eval +
// register DP with early death exit, greedy via endpoint backwalk, backtrack,
// anchors -> ws staging}. Blocks B..B+ZB-1 = pure zero-fill of the 135MB
// output at full write BW (concurrent; DP hidden under it).
__global__ __launch_bounds__(1024, 1) void fused_kernel(const float* __restrict__ tok,
                                                        float4* __restrict__ anchors,
                                                        int* __restrict__ meta,
                                                        float4* __restrict__ outz,
                                                        long total4, int B) {
    const int bid = blockIdx.x;
    const int t = threadIdx.x;

    if (bid >= B) {
        long i = (long)(bid - B) * 1024 + t;
        const long stride = (long)ZB * 1024;
        float4 z = make_float4(0.f, 0.f, 0.f, 0.f);
        for (; i < total4; i += stride) outz[i] = z;
        return;
    }

    const int b = bid;
    const float* T = tok + (size_t)b * WN * KN * CN;
    const int kp = t & 31;        // edge: prev token
    const int knn = t >> 5;       // edge: cur token (0..31)

    __shared__ float sm_snr[WN * KN];          // 16 KB
    __shared__ float sm_tot[WN * KN];          // 16 KB
    __shared__ signed char sm_prev[WN * KN];   // 4 KB
    __shared__ unsigned sm_cmask[CW * KN];     // 2 KB (chunk-local masks)
    __shared__ unsigned s_cun[CW];             // chunk union-of-masks
    __shared__ int s_wstop;                    // first w not computed
    __shared__ int s_alive;
    __shared__ unsigned long long s_key[KN];
    __shared__ unsigned char s_path[KN][WN];   // 4 KB
    __shared__ float s_d[KN][NBND];            // 16.5 KB
    __shared__ int s_we[KN];
    __shared__ int s_e[KN];

    // ---- stage snr (tok[...,0]) into LDS
    for (int i = t; i < WN * KN; i += 1024) sm_snr[i] = T[(size_t)i * CN];
    if (t < KN) { s_key[t] = 0ull; s_we[t] = -1; }
    if (t == 0) { s_wstop = WN; s_alive = 1; }
    __syncthreads();

    float best = NEGF;                         // DP carry (wave0 lanes only)
    if (t < 64) {
        float s0 = sm_snr[t & 31];
        best = (s0 > 0.0f) ? s0 : NEGF;
    }

    // ---- chunked edge eval + DP; chains die fast -> usually 1 chunk
    for (int c0 = 1; c0 < WN; c0 += CW) {
        const int cend = (c0 + CW < WN) ? (c0 + CW) : WN;
        const int cn = cend - c0;
        if (t < CW) s_cun[t] = 0u;
        __syncthreads();

        // edge feasibility for transitions into windows [c0, cend)
        for (int ci = 0; ci < cn; ++ci) {
            const int wi = c0 - 1 + ci;        // prev window
            const float* Tp = T + ((size_t)wi * KN + kp) * CN;
            const float* Tc = T + ((size_t)(wi + 1) * KN + knn) * CN;
            float fe = Tp[4], fs = Tc[3];
            float fm = (fe + fs) * 0.5f;
            bool ok_f = (fm <= 0.0f) || (fabsf(fe - fs) / (fm > 0.0f ? fm : 1.0f) <= 0.05f);
            float dphi = wrapf(Tc[7] - Tp[8]);
            bool ok_p = fabsf(dphi) <= 0.5f;
            float ae = Tp[6], an = Tc[5];
            float am = fmaxf(ae, an);
            bool ok_a = (am <= 0.0f) || (fabsf(ae - an) / (am > 0.0f ? am : 1.0f) <= 0.5f);
            bool ok = (Tp[0] > 0.0f) && (Tc[0] > 0.0f) && ok_f && ok_p && ok_a;

            unsigned long long bal = __ballot(ok);
            int lw = t & 63;
            unsigned lo = (unsigned)(bal & 0xffffffffull);
            unsigned hi = (unsigned)(bal >> 32);
            if (lw == 0) {
                sm_cmask[ci * KN + knn] = lo;
                if ((lo | hi) != 0u) atomicOr(&s_cun[ci], lo | hi);
            } else if (lw == 32) {
                sm_cmask[ci * KN + knn] = hi;
            }
        }
        __syncthreads();

        // DP steps w in [c0, cend) on wave 0; register-resident carry
        if (t < 64) {
            __builtin_amdgcn_s_setprio(1);
            const int kn = t & 31;
            unsigned cun = (t < cn) ? s_cun[t] : 0u;     // for readlane
            unsigned mask_cur = sm_cmask[kn];
            float sn_cur = sm_snr[c0 * KN + kn];
            for (int w = c0; w < cend; ++w) {
                const int ci = w - c0;
                unsigned mask_nxt = 0u; float sn_nxt = 0.0f;
                if (w + 1 < cend) {
                    mask_nxt = sm_cmask[(ci + 1) * KN + kn];
                    sn_nxt = sm_snr[(w + 1) * KN + kn];
                }
                unsigned un = (unsigned)__builtin_amdgcn_readlane((int)cun, ci);
                float v = NEGF;
                int idx = 0;
                while (un) {                              // sparse: ~few bits
                    int i = __builtin_ctz(un);
                    un &= un - 1u;
                    float bv = __int_as_float(
                        __builtin_amdgcn_readlane(__float_as_int(best), i));
                    bool c = ((mask_cur >> i) & 1u) && (bv > v);  // strict > = first-argmax
                    v = c ? bv : v;
                    idx = c ? i : idx;
                }
                bool reached = v > -5e29f;                // bf > NEG*0.5
                float te = v + sn_cur;
                if (t < 32) {
                    sm_prev[w * KN + kn] = reached ? (signed char)idx : (signed char)-1;
                    sm_tot[w * KN + kn] = te;
                }
                best = reached ? te : NEGF;
                mask_cur = mask_nxt;
                sn_cur = sn_nxt;
            }
            unsigned long long alv = __ballot(best > NEGF);
            if (t == 0) {
                s_alive = (alv != 0ull) ? 1 : 0;
                if (alv == 0ull) s_wstop = cend;
            }
            __builtin_amdgcn_s_setprio(0);
        }
        __syncthreads();
        if (!s_alive) break;                              // monotone death
    }

    // ---- fill prev = -1 for never-computed steps
    const int wstop = s_wstop;
    for (int i2 = wstop * KN + t; i2 < WN * KN; i2 += 1024) sm_prev[i2] = (signed char)-1;
    __syncthreads();

    // ---- greedy == per-root argmax(total): backwalk each live endpoint
    for (int e = KN + t; e < WN * KN; e += 1024) {
        if (sm_prev[e] >= 0) {
            int kk = e & 31;
            int w2 = e >> 5;
            while (w2 > 0) { kk = sm_prev[w2 * KN + kk]; --w2; }    // root
            unsigned ubk = __float_as_uint(sm_tot[e]);
            ubk ^= (ubk >> 31) ? 0xFFFFFFFFu : 0x80000000u;
            unsigned long long key =
                ((unsigned long long)ubk << 32) | (unsigned long long)(0xFFFFFFFFu - (unsigned)e);
            atomicMax(&s_key[kk], key);
        }
    }
    __syncthreads();

    // ---- backtrack selected chain per root (32 lanes in parallel)
    if (t < KN) {
        unsigned long long key = s_key[t];
        int we = -1, e = -1;
        if (key != 0ull) {
            e = (int)(0xFFFFFFFFu - (unsigned)(key & 0xFFFFFFFFull));
            we = e >> 5;
            int k = e & 31;
            for (int ww = we; ww > 0; --ww) {
                s_path[t][ww] = (unsigned char)k;
                k = sm_prev[ww * KN + k];
            }
            s_path[t][0] = (unsigned char)k;
        }
        s_we[t] = we;
        s_e[t] = e;
        meta[b * KN + t] = we;
        meta[(size_t)B * KN + b * KN + t] = e;
    }
    __syncthreads();

    // ---- phase increments d_j + anchor A/t/f into ws staging (all waves)
    for (int u = t; u < KN * NBND; u += 1024) {
        int r = u / NBND, bp = u - r * NBND;
        int we = s_we[r];
        if (we < 0) continue;
        if (bp <= we) {
            float dv;
            int pj = s_path[r][bp];
            if (bp == 0) {
                const float* Tq = T + pj * CN;
                dv = Tq[8] - Tq[7];              // d_first = pe0 - ps0 (ws == 0)
            } else {
                int pm = s_path[r][bp - 1];
                float pe_prev = T[((bp - 1) * KN + pm) * CN + 8];
                float psj = T[(bp * KN + pj) * CN + 7];
                float pej = T[(bp * KN + pj) * CN + 8];
                dv = wrapf(psj - pe_prev) + pej - psj;
            }
            s_d[r][bp] = dv;
        }
        int L = we + 1;
        if (bp <= L) {
            float aA, at, af;
            if (bp == 0) {
                const float* Tq = T + (int)s_path[r][0] * CN;
                at = Tq[1]; af = Tq[3]; aA = Tq[5];
            } else if (bp == L) {
                const float* Tq = T + (we * KN + (int)s_path[r][we]) * CN;
                at = Tq[2]; af = Tq[4]; aA = Tq[6];
            } else {
                const float* Ta = T + ((bp - 1) * KN + (int)s_path[r][bp - 1]) * CN;
                const float* Tb = T + (bp * KN + (int)s_path[r][bp]) * CN;
                at = (Ta[2] + Tb[1]) * 0.5f;
                af = (Ta[4] + Tb[3]) * 0.5f;
                aA = (Ta[6] + Tb[5]) * 0.5f;
            }
            float* arow = (float*)(anchors + ((size_t)b * KN + r) * NBND + bp);
            arow[0] = aA; arow[1] = at; arow[3] = af;   // [2]=phi below
        }
    }
    __syncthreads();

    // ---- serial phase cumsum per root into staging
    if (t < KN && s_we[t] >= 0) {
        int we = s_we[t];
        int p0 = s_path[t][0];
        float cum = T[p0 * CN + 7];              // ps0
        float* arow = (float*)(anchors + ((size_t)b * KN + t) * NBND);
        arow[2] = cum;
        for (int j = 0; j <= we; ++j) {
            cum += s_d[t][j];
            arow[(j + 1) * 4 + 2] = cum;
        }
    }
}

// Tiny scatter: copy the <=32 finished anchor rows per batch over the zeros.
__global__ __launch_bounds__(256) void scatter_kernel(const float4* __restrict__ anchors,
                                                      const int* __restrict__ meta,
                                                      float4* __restrict__ out, int B) {
    const int b = blockIdx.x;
    const int t = threadIdx.x;
    for (int u = t; u < KN * NBND; u += 256) {
        int r = u / NBND, bp = u - r * NBND;
        int we = meta[b * KN + r];
        if (we < 0 || bp > we + 1) continue;
        int e = meta[(size_t)B * KN + b * KN + r];
        out[((size_t)b * (WN * KN) + e) * NBND + bp] =
            anchors[((size_t)b * KN + r) * NBND + bp];
    }
}

extern "C" void kernel_launch(void* const* d_in, const int* in_sizes, int n_in,
                              void* d_out, int out_size, void* d_ws, size_t ws_size,
                              hipStream_t stream) {
    const float* tok = (const float*)d_in[0];
    int B = in_sizes[0] / (WN * KN * CN);

    size_t off = 0;
    float4* anchors = (float4*)d_ws;
    off += (size_t)B * KN * NBND * sizeof(float4);
    off = (off + 255) & ~(size_t)255;
    int* meta = (int*)((char*)d_ws + off);

    long total4 = (long)out_size / 4;

    hipLaunchKernelGGL(fused_kernel, dim3(B + ZB), dim3(1024), 0, stream,
                       tok, anchors, meta, (float4*)d_out, total4, B);
    hipLaunchKernelGGL(scatter_kernel, dim3(B), dim3(256), 0, stream,
                       anchors, meta, (float4*)d_out, B);
}